// Round 1
// baseline (350.387 us; speedup 1.0000x reference)
//
#include <hip/hip_runtime.h>
#include <math.h>

// HMM forward (logZ) for K=64 tags, V=50000, D=128, BATCH=8192, L=126.
// Strategy: linear-space forward with a constant 2^16 per-step scale folded
// into the emission table. alpha stays in normal f32 range for the entire
// 126-step scan (per-step net factor ~e^+0.27, final ~e^34).
//
// ws layout:
//   [0, 12,800,000)            btn[v][k]  f32  emission probs * 65536, rows BOS/EOS = 0
//   [12,800,000, +16384)       A[i][j]    f32  softmax(WA, col BOS = -inf) + EPS
//   [12,816,384, +256)         sumexp[k]  f32  softmax denominators for B

#define KT 64
#define VV 50000
#define DD 128
#define BOS_T 62
#define EOS_T 63
#define LLEN 126
#define EPSF 1e-45f
#define SCALE_F 65536.0f
// 126 steps * 16 bits * ln2
#define LOG_TOTAL_SCALE (2016.0f * 0.6931471805599453f)

#define BTN_OFF   0
#define A_OFF     12800000
#define SUM_OFF   12816384

// ---------------------------------------------------------------- A = softmax(WA masked)
__global__ __launch_bounds__(64) void k_prepA(const float* __restrict__ WA,
                                              float* __restrict__ A,
                                              float* __restrict__ sumexp) {
    int i = blockIdx.x;      // row
    int j = threadIdx.x;     // col
    if (i == 0) sumexp[j] = 0.0f;   // zero accumulators for k_emit
    float wv = WA[i * KT + j];
    float e = (j == BOS_T) ? 0.0f : __expf(wv);   // WA in [0,0.01] -> no max-sub needed
    float s = e;
#pragma unroll
    for (int off = 32; off > 0; off >>= 1) s += __shfl_xor(s, off, 64);
    A[i * KT + j] = e / s + EPSF;
}

// ---------------------------------------------------------------- btn[v][k] = exp(ThetaB[k].E[v]), sumexp[k] += ...
__global__ __launch_bounds__(256) void k_emit(const float* __restrict__ ThetaB,
                                              const float* __restrict__ E,
                                              float* __restrict__ btn,
                                              float* __restrict__ sumexp) {
    __shared__ float shT[DD * KT];   // [d][k], conflict-free reads (lane=k contiguous)
    int t = threadIdx.x;
    for (int idx = t; idx < DD * KT; idx += 256) {
        int d = idx >> 6, k = idx & 63;
        shT[idx] = ThetaB[k * DD + d];
    }
    __syncthreads();

    int lane = t & 63;           // k
    int w    = t >> 6;           // wave in block
    int v0   = blockIdx.x * 256 + w * 64;

    float lsum = 0.0f;
    for (int it = 0; it < 8; ++it) {
        int vb = v0 + it * 8;
        float acc[8] = {0, 0, 0, 0, 0, 0, 0, 0};
        for (int dq = 0; dq < 32; ++dq) {
            float t0 = shT[(dq * 4 + 0) * KT + lane];
            float t1 = shT[(dq * 4 + 1) * KT + lane];
            float t2 = shT[(dq * 4 + 2) * KT + lane];
            float t3 = shT[(dq * 4 + 3) * KT + lane];
#pragma unroll
            for (int m = 0; m < 8; ++m) {
                int vc = vb + m;
                vc = vc < VV ? vc : VV - 1;
                const float4 e4 = *(const float4*)(E + (size_t)vc * DD + dq * 4);
                acc[m] = fmaf(e4.x, t0, acc[m]);
                acc[m] = fmaf(e4.y, t1, acc[m]);
                acc[m] = fmaf(e4.z, t2, acc[m]);
                acc[m] = fmaf(e4.w, t3, acc[m]);
            }
        }
#pragma unroll
        for (int m = 0; m < 8; ++m) {
            int v = vb + m;
            if (v < VV) {
                float e = __expf(acc[m]);   // |logit| < ~0.35 -> safe
                btn[(size_t)v * KT + lane] = e;
                lsum += e;
            }
        }
    }
    atomicAdd(&sumexp[lane], lsum);
}

// ---------------------------------------------------------------- btn *= SCALE/sumexp[k]; rows BOS/EOS -> 0
__global__ __launch_bounds__(256) void k_norm(float* __restrict__ btn,
                                              const float* __restrict__ sumexp) {
    __shared__ float rs[KT];
    int t = threadIdx.x;
    if (t < KT) {
        float s = sumexp[t];
        rs[t] = (t == BOS_T || t == EOS_T) ? 0.0f : (SCALE_F / s);
    }
    __syncthreads();
    float4* b4 = (float4*)btn;
    const int n4 = VV * (KT / 4);   // 800000
    int i = blockIdx.x * 256 + t;
    if (i < n4) {
        float4 x = b4[i];
        int k0 = (i & 15) << 2;
        x.x *= rs[k0 + 0];
        x.y *= rs[k0 + 1];
        x.z *= rs[k0 + 2];
        x.w *= rs[k0 + 3];
        b4[i] = x;
    }
}

// ---------------------------------------------------------------- forward scan: 1 wave = 1 sentence, lane = tag
__global__ __launch_bounds__(256, 4) void k_fwd(const int* __restrict__ words,
                                                const float* __restrict__ btn,
                                                const float* __restrict__ A,
                                                float* __restrict__ out) {
    __shared__ __attribute__((aligned(16))) float sh[4][KT];
    int lane = threadIdx.x & 63;
    int w    = threadIdx.x >> 6;
    int b    = blockIdx.x * 4 + w;

    // A column for this lane (j = lane): Ac[i] = A[i][lane]
    float Ac[KT];
#pragma unroll
    for (int i = 0; i < KT; ++i) Ac[i] = A[i * KT + lane];
    float Afin = A[lane * KT + EOS_T];

    const int* wrow = words + (size_t)b * LLEN;
    float alpha = (lane == BOS_T) ? 1.0f : 0.0f;

    int wd = wrow[0];
    float bv = btn[(size_t)wd * KT + lane];

    for (int l = 0; l < LLEN; ++l) {
        // prefetch next step's emission row while computing this step
        float bvn = 0.0f;
        if (l + 1 < LLEN) {
            int wn = wrow[l + 1];
            bvn = btn[(size_t)wn * KT + lane];
        }
        // publish alpha to the wave-private LDS row (wave-synchronous, no barrier)
        sh[w][lane] = alpha;
        asm volatile("s_waitcnt lgkmcnt(0)" ::: "memory");
        float m = 0.0f;
#pragma unroll
        for (int i = 0; i < KT; i += 4) {
            float4 a4 = *(const float4*)&sh[w][i];   // broadcast read, conflict-free
            m = fmaf(a4.x, Ac[i + 0], m);
            m = fmaf(a4.y, Ac[i + 1], m);
            m = fmaf(a4.z, Ac[i + 2], m);
            m = fmaf(a4.w, Ac[i + 3], m);
        }
        alpha = m * bv;
        bv = bvn;
    }

    float val = alpha * Afin;
#pragma unroll
    for (int off = 32; off > 0; off >>= 1) val += __shfl_xor(val, off, 64);
    if (lane == 0) out[b] = logf(val) - LOG_TOTAL_SCALE;
}

extern "C" void kernel_launch(void* const* d_in, const int* in_sizes, int n_in,
                              void* d_out, int out_size, void* d_ws, size_t ws_size,
                              hipStream_t stream) {
    const int*   words  = (const int*)d_in[0];     // [8192,126]
    const float* ThetaB = (const float*)d_in[1];   // [64,128]
    const float* WA     = (const float*)d_in[2];   // [64,64]
    const float* E      = (const float*)d_in[3];   // [50000,128]
    float* out = (float*)d_out;                    // [8192]

    char* ws = (char*)d_ws;
    float* btn    = (float*)(ws + BTN_OFF);
    float* A      = (float*)(ws + A_OFF);
    float* sumexp = (float*)(ws + SUM_OFF);

    k_prepA<<<64, 64, 0, stream>>>(WA, A, sumexp);
    k_emit<<<(VV + 255) / 256, 256, 0, stream>>>(ThetaB, E, btn, sumexp);
    k_norm<<<(VV * (KT / 4) + 255) / 256, 256, 0, stream>>>(btn, sumexp);
    k_fwd<<<8192 / 4, 256, 0, stream>>>(words, btn, A, out);
}

// Round 2
// 334.731 us; speedup vs baseline: 1.0468x; 1.0468x over previous
//
#include <hip/hip_runtime.h>
#include <math.h>

// HMM forward (logZ) for K=64 tags, V=50000, D=128, BATCH=8192, L=126.
// Linear-space forward with constant 2^16/step scale folded into the emission
// table; alpha stays in normal f32 range for all 126 steps.
//
// ws layout:
//   [0, 12,800,000)            btn[v][k]  f32  emission probs * 65536, rows BOS/EOS = 0
//   [12,800,000, +16384)       A[i][j]    f32  softmax(WA, col BOS = -inf) + EPS
//   [12,816,384, +256)         sumexp[k]  f32  softmax denominators for B

#define KT 64
#define VV 50000
#define DD 128
#define BOS_T 62
#define EOS_T 63
#define LLEN 126
#define EPSF 1e-45f
#define SCALE_F 65536.0f
#define LOG_TOTAL_SCALE (2016.0f * 0.6931471805599453f)

#define BTN_OFF   0
#define A_OFF     12800000
#define SUM_OFF   12816384

// ---------------------------------------------------------------- A = softmax(WA masked)
__global__ __launch_bounds__(64) void k_prepA(const float* __restrict__ WA,
                                              float* __restrict__ A,
                                              float* __restrict__ sumexp) {
    int i = blockIdx.x;      // row
    int j = threadIdx.x;     // col
    if (i == 0) sumexp[j] = 0.0f;   // zero accumulators for k_emit
    float wv = WA[i * KT + j];
    float e = (j == BOS_T) ? 0.0f : __expf(wv);   // WA in [0,0.01] -> no max-sub needed
    float s = e;
#pragma unroll
    for (int off = 32; off > 0; off >>= 1) s += __shfl_xor(s, off, 64);
    A[i * KT + j] = e / s + EPSF;
}

// ---------------------------------------------------------------- btn[v][k] = exp(ThetaB[k].E[v])
// 8 v-rows per wave, 4 waves/block -> 32 rows/block, 1563 blocks (~20 waves/CU).
__global__ __launch_bounds__(256) void k_emit(const float* __restrict__ ThetaB,
                                              const float* __restrict__ E,
                                              float* __restrict__ btn,
                                              float* __restrict__ sumexp) {
    __shared__ float shT[DD * KT];   // [d][k], 32 KB; lane=k stride-1 reads (conflict-free)
    __shared__ float red[4 * KT];
    int t = threadIdx.x;
    for (int idx = t; idx < DD * KT; idx += 256) {
        int d = idx >> 6, k = idx & 63;
        shT[idx] = ThetaB[k * DD + d];
    }
    __syncthreads();

    int lane = t & 63;           // k
    int w    = t >> 6;           // wave in block
    int vb   = (blockIdx.x * 4 + w) * 8;   // first of 8 v-rows for this wave

    float acc[8] = {0, 0, 0, 0, 0, 0, 0, 0};
    for (int dq = 0; dq < 32; ++dq) {
        float t0 = shT[(dq * 4 + 0) * KT + lane];
        float t1 = shT[(dq * 4 + 1) * KT + lane];
        float t2 = shT[(dq * 4 + 2) * KT + lane];
        float t3 = shT[(dq * 4 + 3) * KT + lane];
#pragma unroll
        for (int m = 0; m < 8; ++m) {
            int vc = vb + m;
            vc = vc < VV ? vc : VV - 1;
            const float4 e4 = *(const float4*)(E + (size_t)vc * DD + dq * 4);
            acc[m] = fmaf(e4.x, t0, acc[m]);
            acc[m] = fmaf(e4.y, t1, acc[m]);
            acc[m] = fmaf(e4.z, t2, acc[m]);
            acc[m] = fmaf(e4.w, t3, acc[m]);
        }
    }
    float lsum = 0.0f;
#pragma unroll
    for (int m = 0; m < 8; ++m) {
        int v = vb + m;
        if (v < VV) {
            float e = __expf(acc[m]);   // |logit| < ~0.35 -> safe
            btn[(size_t)v * KT + lane] = e;
            lsum += e;
        }
    }
    // block-level reduction -> 1 atomic per k per block (avoid 6250-deep atomic chains)
    red[w * KT + lane] = lsum;
    __syncthreads();
    if (w == 0) {
        float s = red[lane] + red[KT + lane] + red[2 * KT + lane] + red[3 * KT + lane];
        atomicAdd(&sumexp[lane], s);
    }
}

// ---------------------------------------------------------------- btn *= SCALE/sumexp[k]; rows BOS/EOS -> 0
__global__ __launch_bounds__(256) void k_norm(float* __restrict__ btn,
                                              const float* __restrict__ sumexp) {
    __shared__ float rs[KT];
    int t = threadIdx.x;
    if (t < KT) {
        float s = sumexp[t];
        rs[t] = (t == BOS_T || t == EOS_T) ? 0.0f : (SCALE_F / s);
    }
    __syncthreads();
    float4* b4 = (float4*)btn;
    const int n4 = VV * (KT / 4);   // 800000
    int i = blockIdx.x * 256 + t;
    if (i < n4) {
        float4 x = b4[i];
        int k0 = (i & 15) << 2;
        x.x *= rs[k0 + 0];
        x.y *= rs[k0 + 1];
        x.z *= rs[k0 + 2];
        x.w *= rs[k0 + 3];
        b4[i] = x;
    }
}

// ---------------------------------------------------------------- forward scan: 1 wave = 1 sentence, lane = tag
__global__ __launch_bounds__(256, 4) void k_fwd(const int* __restrict__ words,
                                                const float* __restrict__ btn,
                                                const float* __restrict__ A,
                                                float* __restrict__ out) {
    __shared__ __attribute__((aligned(16))) float sh[4][KT];
    int lane = threadIdx.x & 63;
    int w    = threadIdx.x >> 6;
    int b    = blockIdx.x * 4 + w;

    // A column for this lane (j = lane): Ac[i] = A[i][lane]
    float Ac[KT];
#pragma unroll
    for (int i = 0; i < KT; ++i) Ac[i] = A[i * KT + lane];
    // Pin Ac into VGPRs: opaque to the compiler so the loads above cannot be
    // rematerialized inside the scan loop (round-1 showed VGPR_Count=48 ->
    // the A column was being re-fetched every step).
#pragma unroll
    for (int i = 0; i < KT; ++i) asm volatile("" : "+v"(Ac[i]));
    float Afin = A[lane * KT + EOS_T];

    const int* wrow = words + (size_t)b * LLEN;
    float alpha = (lane == BOS_T) ? 1.0f : 0.0f;

    // 2-deep software pipeline on the emission gather (random 256B/L3 latency)
    int w0 = wrow[0];
    int w1 = wrow[1];
    float bv0 = btn[(size_t)w0 * KT + lane];
    float bv1 = btn[(size_t)w1 * KT + lane];

    for (int l = 0; l < LLEN; ++l) {
        float bv2 = 0.0f;
        if (l + 2 < LLEN) {
            int wn = wrow[l + 2];
            bv2 = btn[(size_t)wn * KT + lane];
        }
        // publish alpha to the wave-private LDS row (wave-synchronous, no barrier)
        sh[w][lane] = alpha;
        asm volatile("s_waitcnt lgkmcnt(0)" ::: "memory");
        float m = 0.0f;
#pragma unroll
        for (int i = 0; i < KT; i += 4) {
            float4 a4 = *(const float4*)&sh[w][i];   // broadcast read, conflict-free
            m = fmaf(a4.x, Ac[i + 0], m);
            m = fmaf(a4.y, Ac[i + 1], m);
            m = fmaf(a4.z, Ac[i + 2], m);
            m = fmaf(a4.w, Ac[i + 3], m);
        }
        alpha = m * bv0;
        bv0 = bv1;
        bv1 = bv2;
    }

    float val = alpha * Afin;
#pragma unroll
    for (int off = 32; off > 0; off >>= 1) val += __shfl_xor(val, off, 64);
    if (lane == 0) out[b] = logf(val) - LOG_TOTAL_SCALE;
}

extern "C" void kernel_launch(void* const* d_in, const int* in_sizes, int n_in,
                              void* d_out, int out_size, void* d_ws, size_t ws_size,
                              hipStream_t stream) {
    const int*   words  = (const int*)d_in[0];     // [8192,126]
    const float* ThetaB = (const float*)d_in[1];   // [64,128]
    const float* WA     = (const float*)d_in[2];   // [64,64]
    const float* E      = (const float*)d_in[3];   // [50000,128]
    float* out = (float*)d_out;                    // [8192]

    char* ws = (char*)d_ws;
    float* btn    = (float*)(ws + BTN_OFF);
    float* A      = (float*)(ws + A_OFF);
    float* sumexp = (float*)(ws + SUM_OFF);

    k_prepA<<<64, 64, 0, stream>>>(WA, A, sumexp);
    k_emit<<<(VV + 31) / 32, 256, 0, stream>>>(ThetaB, E, btn, sumexp);
    k_norm<<<(VV * (KT / 4) + 255) / 256, 256, 0, stream>>>(btn, sumexp);
    k_fwd<<<8192 / 4, 256, 0, stream>>>(words, btn, A, out);
}

// Round 4
// 218.486 us; speedup vs baseline: 1.6037x; 1.5320x over previous
//
#include <hip/hip_runtime.h>
#include <hip/hip_bf16.h>
#include <math.h>

// HMM forward (logZ), K=64 tags, V=50000, D=128, BATCH=8192, L=126.
// MFMA formulation: alpha_next[16 sent][64 tag] = (alpha x T) .* btn[word],
// with constant 2^16/step scale folded into the bf16 emission table btn.
//
// ws layout:
//   [0, 6,400,000)        btn_bf[v][k]  bf16  emission*65536, cols BOS/EOS=0
//   [6,400,000, +16384)   A[i][j]       f32   softmax(WA, col BOS=-inf)+EPS
//   [6,416,384, +256)     sumexp[k]     f32

#define KT 64
#define VV 50000
#define DD 128
#define BOS_T 62
#define EOS_T 63
#define LLEN 126
#define EPSF 1e-45f
#define SCALE_F 65536.0f
#define LOG_TOTAL_SCALE (2016.0f * 0.6931471805599453f)
#define PITCH 68   // f32 row pitch of LDS alpha tile

#define BTN_OFF   0
#define A_OFF     6400000
#define SUM_OFF   6416384

typedef short short8 __attribute__((ext_vector_type(8)));
typedef float f32x4  __attribute__((ext_vector_type(4)));

union U8 { short8 v; unsigned u[4]; short s[8]; };

static __device__ inline unsigned short f2bf_u(float x) {
    __hip_bfloat16 h = __float2bfloat16(x);
    return *reinterpret_cast<unsigned short*>(&h);
}
static __device__ inline short f2bf(float x) { return (short)f2bf_u(x); }
static __device__ inline unsigned pk2(float a, float b) {
    return (unsigned)f2bf_u(a) | ((unsigned)f2bf_u(b) << 16);
}
static __device__ inline float lo16(unsigned u) { union { unsigned i; float f; } c; c.i = u << 16;        return c.f; }
static __device__ inline float hi16(unsigned u) { union { unsigned i; float f; } c; c.i = u & 0xffff0000u; return c.f; }

// ---------------------------------------------------------------- A = softmax(WA masked) + zero sumexp
__global__ __launch_bounds__(64) void k_prepA(const float* __restrict__ WA,
                                              float* __restrict__ A,
                                              float* __restrict__ sumexp) {
    int i = blockIdx.x;
    int j = threadIdx.x;
    if (i == 0) sumexp[j] = 0.0f;
    float wv = WA[i * KT + j];
    float e = (j == BOS_T) ? 0.0f : __expf(wv);
    float s = e;
#pragma unroll
    for (int off = 32; off > 0; off >>= 1) s += __shfl_xor(s, off, 64);
    A[i * KT + j] = e / s + EPSF;
}

// ---------------------------------------------------------------- btn_bf[v][k] = bf16(exp(E[v].ThetaB[k]))  (MFMA GEMM)
// wave = 16 v-rows, block = 4 waves = 64 rows, grid 782.
__global__ __launch_bounds__(256) void k_emit(const float* __restrict__ ThetaB,
                                              const float* __restrict__ E,
                                              unsigned short* __restrict__ btn_bf,
                                              float* __restrict__ sumexp) {
    int t    = threadIdx.x;
    int lane = t & 63;
    int w    = t >> 6;
    int n    = lane & 15;
    int q    = lane >> 4;
    int v0   = (blockIdx.x * 4 + w) * 16;

    // B-frags: ThetaB^T as B[k=d][n=tag]; frag (kt,nt) reg j = ThetaB[nt*16+n][kt*32+q*8+j]
    short8 Bf[4][4];
#pragma unroll
    for (int kt = 0; kt < 4; ++kt)
#pragma unroll
        for (int nt = 0; nt < 4; ++nt) {
            const float* p = ThetaB + (nt * 16 + n) * DD + kt * 32 + q * 8;
            float4 x = *(const float4*)p;
            float4 y = *(const float4*)(p + 4);
            U8 f;
            f.u[0] = pk2(x.x, x.y); f.u[1] = pk2(x.z, x.w);
            f.u[2] = pk2(y.x, y.y); f.u[3] = pk2(y.z, y.w);
            Bf[kt][nt] = f.v;
        }

    // A-frags: E rows; A[m=lane&15][k=q*8+j] per ktile
    int rowE = v0 + n; rowE = rowE < VV ? rowE : VV - 1;
    short8 Ae[4];
#pragma unroll
    for (int kt = 0; kt < 4; ++kt) {
        const float* p = E + (size_t)rowE * DD + kt * 32 + q * 8;
        float4 x = *(const float4*)p;
        float4 y = *(const float4*)(p + 4);
        U8 f;
        f.u[0] = pk2(x.x, x.y); f.u[1] = pk2(x.z, x.w);
        f.u[2] = pk2(y.x, y.y); f.u[3] = pk2(y.z, y.w);
        Ae[kt] = f.v;
    }

    float psum[4];
#pragma unroll
    for (int nt = 0; nt < 4; ++nt) {
        f32x4 C = {0.f, 0.f, 0.f, 0.f};
#pragma unroll
        for (int kt = 0; kt < 4; ++kt)
            C = __builtin_amdgcn_mfma_f32_16x16x32_bf16(Ae[kt], Bf[kt][nt], C, 0, 0, 0);
        float ps = 0.0f;
#pragma unroll
        for (int r = 0; r < 4; ++r) {
            int row = v0 + 4 * q + r;
            float e = __expf(C[r]);
            if (row < VV) {
                btn_bf[(size_t)row * KT + nt * 16 + n] = f2bf_u(e);
                ps += e;
            }
        }
        psum[nt] = ps;
    }
    // reduce over the 4 q-groups (lane bits 4,5), then one atomic per tag
#pragma unroll
    for (int nt = 0; nt < 4; ++nt) {
        float s = psum[nt];
        s += __shfl_xor(s, 16, 64);
        s += __shfl_xor(s, 32, 64);
        if (q == 0) atomicAdd(&sumexp[nt * 16 + n], s);
    }
}

// ---------------------------------------------------------------- btn_bf *= SCALE/sumexp[k]; cols BOS/EOS -> 0
__global__ __launch_bounds__(256) void k_norm(unsigned short* __restrict__ btn_bf,
                                              const float* __restrict__ sumexp) {
    __shared__ float rs[KT];
    int t = threadIdx.x;
    if (t < KT) {
        float s = sumexp[t];
        rs[t] = (t == BOS_T || t == EOS_T) ? 0.0f : (SCALE_F / s);
    }
    __syncthreads();
    uint4* b4 = (uint4*)btn_bf;
    const int n8 = VV * KT / 8;   // 400000 uint4s (8 bf16 each)
    int i = blockIdx.x * 256 + t;
    if (i < n8) {
        uint4 x = b4[i];
        int k0 = (i & 7) * 8;
        unsigned r0 = pk2(lo16(x.x) * rs[k0 + 0], hi16(x.x) * rs[k0 + 1]);
        unsigned r1 = pk2(lo16(x.y) * rs[k0 + 2], hi16(x.y) * rs[k0 + 3]);
        unsigned r2 = pk2(lo16(x.z) * rs[k0 + 4], hi16(x.z) * rs[k0 + 5]);
        unsigned r3 = pk2(lo16(x.w) * rs[k0 + 6], hi16(x.w) * rs[k0 + 7]);
        b4[i] = make_uint4(r0, r1, r2, r3);
    }
}

// ---------------------------------------------------------------- forward scan: 1 wave = 16 sentences, MFMA
__global__ __launch_bounds__(64) void k_fwd(const int* __restrict__ words,
                                            const unsigned short* __restrict__ btn_bf,
                                            const float* __restrict__ A,
                                            float* __restrict__ out) {
    __shared__ __attribute__((aligned(16))) float sh[16 * PITCH];
    int lane = threadIdx.x & 63;
    int n    = lane & 15;     // B-frag col / C col / A-frag row (sentence on read side)
    int q    = lane >> 4;
    int b0   = blockIdx.x * 16;

    // B-frags of the transition matrix: frag(kt,nt) reg j = T[kt*32+q*8+j][nt*16+n]
    short8 Bf[2][4];
#pragma unroll
    for (int kt = 0; kt < 2; ++kt)
#pragma unroll
        for (int nt = 0; nt < 4; ++nt) {
            U8 f;
#pragma unroll
            for (int j = 0; j < 8; ++j)
                f.s[j] = f2bf(A[(kt * 32 + q * 8 + j) * KT + nt * 16 + n]);
            Bf[kt][nt] = f.v;
        }
    // final-step frag: column 0 = A[k][EOS], rest 0
    short8 Bfin[2];
#pragma unroll
    for (int kt = 0; kt < 2; ++kt) {
        U8 f;
#pragma unroll
        for (int j = 0; j < 8; ++j)
            f.s[j] = (n == 0) ? f2bf(A[(kt * 32 + q * 8 + j) * KT + EOS_T]) : (short)0;
        Bfin[kt] = f.v;
    }

    // alpha A-frags (bf16): alpha0 = one-hot at tag 62 -> kt=1, q=3, slot 6
    U8 a0, a1;
#pragma unroll
    for (int j = 0; j < 4; ++j) { a0.u[j] = 0; a1.u[j] = 0; }
    if (q == 3) a1.s[6] = (short)0x3F80;   // bf16(1.0)
    short8 Af0 = a0.v, Af1 = a1.v;

    const int* wrow = words + (size_t)(b0 + n) * LLEN;
    int wcur  = wrow[0];
    int wnext = wrow[1];
    uint4 e0c = *(const uint4*)(btn_bf + (size_t)wcur * KT + q * 8);
    uint4 e1c = *(const uint4*)(btn_bf + (size_t)wcur * KT + 32 + q * 8);

    for (int l = 0; l < LLEN; ++l) {
        // prefetch next step's emission row + word
        uint4 e0n = *(const uint4*)(btn_bf + (size_t)wnext * KT + q * 8);
        uint4 e1n = *(const uint4*)(btn_bf + (size_t)wnext * KT + 32 + q * 8);
        int wi = l + 2; wi = wi < LLEN ? wi : LLEN - 1;
        int wnn = wrow[wi];

        // C[nt] = alpha x T   (chained over the 2 K-tiles)
        f32x4 C[4];
#pragma unroll
        for (int nt = 0; nt < 4; ++nt) {
            f32x4 acc = {0.f, 0.f, 0.f, 0.f};
            acc = __builtin_amdgcn_mfma_f32_16x16x32_bf16(Af0, Bf[0][nt], acc, 0, 0, 0);
            acc = __builtin_amdgcn_mfma_f32_16x16x32_bf16(Af1, Bf[1][nt], acc, 0, 0, 0);
            C[nt] = acc;
        }

        // write C (f32) to LDS tile [sent m][tag k], m = 4q+r, k = nt*16+n
#pragma unroll
        for (int nt = 0; nt < 4; ++nt)
#pragma unroll
            for (int r = 0; r < 4; ++r)
                sh[(4 * q + r) * PITCH + nt * 16 + n] = C[nt][r];
        asm volatile("s_waitcnt lgkmcnt(0)" ::: "memory");

        // read back in A-layout (row = sentence n), fold emission, pack bf16
        {
            const float* p = sh + n * PITCH + q * 8;
            float4 lo = *(const float4*)p;
            float4 hi = *(const float4*)(p + 4);
            U8 f;
            f.u[0] = pk2(lo.x * lo16(e0c.x), lo.y * hi16(e0c.x));
            f.u[1] = pk2(lo.z * lo16(e0c.y), lo.w * hi16(e0c.y));
            f.u[2] = pk2(hi.x * lo16(e0c.z), hi.y * hi16(e0c.z));
            f.u[3] = pk2(hi.z * lo16(e0c.w), hi.w * hi16(e0c.w));
            Af0 = f.v;
        }
        {
            const float* p = sh + n * PITCH + 32 + q * 8;
            float4 lo = *(const float4*)p;
            float4 hi = *(const float4*)(p + 4);
            U8 f;
            f.u[0] = pk2(lo.x * lo16(e1c.x), lo.y * hi16(e1c.x));
            f.u[1] = pk2(lo.z * lo16(e1c.y), lo.w * hi16(e1c.y));
            f.u[2] = pk2(hi.x * lo16(e1c.z), hi.y * hi16(e1c.z));
            f.u[3] = pk2(hi.z * lo16(e1c.w), hi.w * hi16(e1c.w));
            Af1 = f.v;
        }
        e0c = e0n; e1c = e1n;
        wnext = wnn;
    }

    // logZ = log(sum_j alpha[j] * A[j][EOS]) - total scale
    f32x4 Cf = {0.f, 0.f, 0.f, 0.f};
    Cf = __builtin_amdgcn_mfma_f32_16x16x32_bf16(Af0, Bfin[0], Cf, 0, 0, 0);
    Cf = __builtin_amdgcn_mfma_f32_16x16x32_bf16(Af1, Bfin[1], Cf, 0, 0, 0);
    if (n == 0) {
#pragma unroll
        for (int r = 0; r < 4; ++r)
            out[b0 + 4 * q + r] = logf(Cf[r]) - LOG_TOTAL_SCALE;
    }
}

extern "C" void kernel_launch(void* const* d_in, const int* in_sizes, int n_in,
                              void* d_out, int out_size, void* d_ws, size_t ws_size,
                              hipStream_t stream) {
    const int*   words  = (const int*)d_in[0];     // [8192,126]
    const float* ThetaB = (const float*)d_in[1];   // [64,128]
    const float* WA     = (const float*)d_in[2];   // [64,64]
    const float* E      = (const float*)d_in[3];   // [50000,128]
    float* out = (float*)d_out;                    // [8192]

    char* ws = (char*)d_ws;
    unsigned short* btn_bf = (unsigned short*)(ws + BTN_OFF);
    float* A      = (float*)(ws + A_OFF);
    float* sumexp = (float*)(ws + SUM_OFF);

    k_prepA<<<64, 64, 0, stream>>>(WA, A, sumexp);
    k_emit<<<(VV + 63) / 64, 256, 0, stream>>>(ThetaB, E, btn_bf, sumexp);
    k_norm<<<(VV * KT / 8 + 255) / 256, 256, 0, stream>>>(btn_bf, sumexp);
    k_fwd<<<8192 / 16, 64, 0, stream>>>(words, btn_bf, A, out);
}

// Round 5
// 152.532 us; speedup vs baseline: 2.2971x; 1.4324x over previous
//
#include <hip/hip_runtime.h>
#include <hip/hip_bf16.h>
#include <math.h>

// HMM forward (logZ), K=64 tags, V=50000, D=128, BATCH=8192, L=126.
// MFMA formulation: alpha_next[16 sent][64 tag] = (alpha x T) .* btn[word],
// with constant 2^16/step scale folded into the bf16 emission table btn.
//
// ws layout:
//   [0, 6,400,000)        btn_bf[v][k]  bf16  emission*65536, cols BOS/EOS=0
//   [6,400,000, +16384)   A[i][j]       f32   softmax(WA, col BOS=-inf)+EPS
//   [6,416,384, +256)     sumexp[k]     f32
//   [6,416,640, +200704)  partial[k][784] f32 per-block column sums (no atomics:
//                         round-4 showed 200k same-line atomics serialized k_emit at 89us)

#define KT 64
#define VV 50000
#define DD 128
#define BOS_T 62
#define EOS_T 63
#define LLEN 126
#define EPSF 1e-45f
#define SCALE_F 65536.0f
#define LOG_TOTAL_SCALE (2016.0f * 0.6931471805599453f)
#define PITCH 68          // f32 row pitch of LDS alpha tile
#define NBLK 782          // k_emit grid
#define PBLK 784          // padded partial row

#define BTN_OFF   0
#define A_OFF     6400000
#define SUM_OFF   6416384
#define PART_OFF  6416640

typedef short short8 __attribute__((ext_vector_type(8)));
typedef float f32x4  __attribute__((ext_vector_type(4)));

union U8 { short8 v; unsigned u[4]; short s[8]; };

static __device__ inline unsigned short f2bf_u(float x) {
    __hip_bfloat16 h = __float2bfloat16(x);
    return *reinterpret_cast<unsigned short*>(&h);
}
static __device__ inline short f2bf(float x) { return (short)f2bf_u(x); }
static __device__ inline unsigned pk2(float a, float b) {
    return (unsigned)f2bf_u(a) | ((unsigned)f2bf_u(b) << 16);
}
static __device__ inline float lo16(unsigned u) { union { unsigned i; float f; } c; c.i = u << 16;        return c.f; }
static __device__ inline float hi16(unsigned u) { union { unsigned i; float f; } c; c.i = u & 0xffff0000u; return c.f; }

// ---------------------------------------------------------------- A = softmax(WA masked)
__global__ __launch_bounds__(64) void k_prepA(const float* __restrict__ WA,
                                              float* __restrict__ A) {
    int i = blockIdx.x;
    int j = threadIdx.x;
    float wv = WA[i * KT + j];
    float e = (j == BOS_T) ? 0.0f : __expf(wv);
    float s = e;
#pragma unroll
    for (int off = 32; off > 0; off >>= 1) s += __shfl_xor(s, off, 64);
    A[i * KT + j] = e / s + EPSF;
}

// ---------------------------------------------------------------- btn_bf[v][k] = bf16(exp(E[v].ThetaB[k]))  (MFMA GEMM)
// wave = 16 v-rows, block = 4 waves = 64 rows. Column sums -> partial[k][blk].
__global__ __launch_bounds__(256) void k_emit(const float* __restrict__ ThetaB,
                                              const float* __restrict__ E,
                                              unsigned short* __restrict__ btn_bf,
                                              float* __restrict__ partial) {
    __shared__ float red[4][KT];
    int t    = threadIdx.x;
    int lane = t & 63;
    int w    = t >> 6;
    int n    = lane & 15;
    int q    = lane >> 4;
    int v0   = (blockIdx.x * 4 + w) * 16;

    // B-frags: ThetaB^T as B[k=d][n=tag]; frag (kt,nt) reg j = ThetaB[nt*16+n][kt*32+q*8+j]
    short8 Bf[4][4];
#pragma unroll
    for (int kt = 0; kt < 4; ++kt)
#pragma unroll
        for (int nt = 0; nt < 4; ++nt) {
            const float* p = ThetaB + (nt * 16 + n) * DD + kt * 32 + q * 8;
            float4 x = *(const float4*)p;
            float4 y = *(const float4*)(p + 4);
            U8 f;
            f.u[0] = pk2(x.x, x.y); f.u[1] = pk2(x.z, x.w);
            f.u[2] = pk2(y.x, y.y); f.u[3] = pk2(y.z, y.w);
            Bf[kt][nt] = f.v;
        }

    // A-frags: E rows; A[m=lane&15][k=q*8+j] per ktile
    int rowE = v0 + n; rowE = rowE < VV ? rowE : VV - 1;
    short8 Ae[4];
#pragma unroll
    for (int kt = 0; kt < 4; ++kt) {
        const float* p = E + (size_t)rowE * DD + kt * 32 + q * 8;
        float4 x = *(const float4*)p;
        float4 y = *(const float4*)(p + 4);
        U8 f;
        f.u[0] = pk2(x.x, x.y); f.u[1] = pk2(x.z, x.w);
        f.u[2] = pk2(y.x, y.y); f.u[3] = pk2(y.z, y.w);
        Ae[kt] = f.v;
    }

#pragma unroll
    for (int nt = 0; nt < 4; ++nt) {
        f32x4 C = {0.f, 0.f, 0.f, 0.f};
#pragma unroll
        for (int kt = 0; kt < 4; ++kt)
            C = __builtin_amdgcn_mfma_f32_16x16x32_bf16(Ae[kt], Bf[kt][nt], C, 0, 0, 0);
        float ps = 0.0f;
#pragma unroll
        for (int r = 0; r < 4; ++r) {
            int row = v0 + 4 * q + r;
            float e = __expf(C[r]);
            if (row < VV) {
                btn_bf[(size_t)row * KT + nt * 16 + n] = f2bf_u(e);
                ps += e;
            }
        }
        // reduce over the 4 q-groups; all lanes end with the tag's wave-sum
        ps += __shfl_xor(ps, 16, 64);
        ps += __shfl_xor(ps, 32, 64);
        if (q == 0) red[w][nt * 16 + n] = ps;
    }
    __syncthreads();
    if (w == 0) {
        float s = red[0][lane] + red[1][lane] + red[2][lane] + red[3][lane];
        partial[lane * PBLK + blockIdx.x] = s;
    }
}

// ---------------------------------------------------------------- sumexp[k] = sum_blk partial[k][blk]
__global__ __launch_bounds__(256) void k_sum(const float* __restrict__ partial,
                                             float* __restrict__ sumexp) {
    __shared__ float r[4];
    int k = blockIdx.x;
    int t = threadIdx.x;
    float s = 0.0f;
    for (int i = t; i < NBLK; i += 256) s += partial[k * PBLK + i];
#pragma unroll
    for (int off = 32; off > 0; off >>= 1) s += __shfl_xor(s, off, 64);
    if ((t & 63) == 0) r[t >> 6] = s;
    __syncthreads();
    if (t == 0) sumexp[k] = r[0] + r[1] + r[2] + r[3];
}

// ---------------------------------------------------------------- btn_bf *= SCALE/sumexp[k]; cols BOS/EOS -> 0
__global__ __launch_bounds__(256) void k_norm(unsigned short* __restrict__ btn_bf,
                                              const float* __restrict__ sumexp) {
    __shared__ float rs[KT];
    int t = threadIdx.x;
    if (t < KT) {
        float s = sumexp[t];
        rs[t] = (t == BOS_T || t == EOS_T) ? 0.0f : (SCALE_F / s);
    }
    __syncthreads();
    uint4* b4 = (uint4*)btn_bf;
    const int n8 = VV * KT / 8;   // 400000 uint4s (8 bf16 each)
    int i = blockIdx.x * 256 + t;
    if (i < n8) {
        uint4 x = b4[i];
        int k0 = (i & 7) * 8;
        unsigned r0 = pk2(lo16(x.x) * rs[k0 + 0], hi16(x.x) * rs[k0 + 1]);
        unsigned r1 = pk2(lo16(x.y) * rs[k0 + 2], hi16(x.y) * rs[k0 + 3]);
        unsigned r2 = pk2(lo16(x.z) * rs[k0 + 4], hi16(x.z) * rs[k0 + 5]);
        unsigned r3 = pk2(lo16(x.w) * rs[k0 + 6], hi16(x.w) * rs[k0 + 7]);
        b4[i] = make_uint4(r0, r1, r2, r3);
    }
}

// ---------------------------------------------------------------- forward scan: 1 wave = 16 sentences, MFMA
__global__ __launch_bounds__(64) void k_fwd(const int* __restrict__ words,
                                            const unsigned short* __restrict__ btn_bf,
                                            const float* __restrict__ A,
                                            float* __restrict__ out) {
    __shared__ __attribute__((aligned(16))) float sh[16 * PITCH];
    int lane = threadIdx.x & 63;
    int n    = lane & 15;     // sentence (read side) / B col
    int q    = lane >> 4;
    int b0   = blockIdx.x * 16;

    // B-frags of the transition matrix: frag(kt,nt) reg j = T[kt*32+q*8+j][nt*16+n]
    short8 Bf[2][4];
#pragma unroll
    for (int kt = 0; kt < 2; ++kt)
#pragma unroll
        for (int nt = 0; nt < 4; ++nt) {
            U8 f;
#pragma unroll
            for (int j = 0; j < 8; ++j)
                f.s[j] = f2bf(A[(kt * 32 + q * 8 + j) * KT + nt * 16 + n]);
            Bf[kt][nt] = f.v;
        }
    // final-step frag: column 0 = A[k][EOS], rest 0
    short8 Bfin[2];
#pragma unroll
    for (int kt = 0; kt < 2; ++kt) {
        U8 f;
#pragma unroll
        for (int j = 0; j < 8; ++j)
            f.s[j] = (n == 0) ? f2bf(A[(kt * 32 + q * 8 + j) * KT + EOS_T]) : (short)0;
        Bfin[kt] = f.v;
    }

    // alpha A-frags (bf16): alpha0 = one-hot at tag 62 -> kt=1, q=3, slot 6
    U8 a0, a1;
#pragma unroll
    for (int j = 0; j < 4; ++j) { a0.u[j] = 0; a1.u[j] = 0; }
    if (q == 3) a1.s[6] = (short)0x3F80;   // bf16(1.0)
    short8 Af0 = a0.v, Af1 = a1.v;

    const int* wrow = words + (size_t)(b0 + n) * LLEN;

    // 3-deep emission prefetch pipeline (random 128B rows from L2/L3)
    int wa = wrow[0], wb = wrow[1], wc = wrow[2];
    uint4 e0a = *(const uint4*)(btn_bf + (size_t)wa * KT + q * 8);
    uint4 e1a = *(const uint4*)(btn_bf + (size_t)wa * KT + 32 + q * 8);
    uint4 e0b = *(const uint4*)(btn_bf + (size_t)wb * KT + q * 8);
    uint4 e1b = *(const uint4*)(btn_bf + (size_t)wb * KT + 32 + q * 8);
    uint4 e0c = *(const uint4*)(btn_bf + (size_t)wc * KT + q * 8);
    uint4 e1c = *(const uint4*)(btn_bf + (size_t)wc * KT + 32 + q * 8);
    int wn = wrow[3];

    for (int l = 0; l < LLEN; ++l) {
        // issue step-(l+3) prefetch first: no dependents for 3 iterations
        uint4 e0d = *(const uint4*)(btn_bf + (size_t)wn * KT + q * 8);
        uint4 e1d = *(const uint4*)(btn_bf + (size_t)wn * KT + 32 + q * 8);
        int wi = l + 4; wi = wi < LLEN ? wi : LLEN - 1;
        wn = wrow[wi];

        // C[nt] = alpha x T   (chained over the 2 K-tiles)
        f32x4 C[4];
#pragma unroll
        for (int nt = 0; nt < 4; ++nt) {
            f32x4 acc = {0.f, 0.f, 0.f, 0.f};
            acc = __builtin_amdgcn_mfma_f32_16x16x32_bf16(Af0, Bf[0][nt], acc, 0, 0, 0);
            acc = __builtin_amdgcn_mfma_f32_16x16x32_bf16(Af1, Bf[1][nt], acc, 0, 0, 0);
            C[nt] = acc;
        }

        // write C (f32) to LDS tile [sent m][tag k], m = 4q+r, k = nt*16+n
#pragma unroll
        for (int nt = 0; nt < 4; ++nt)
#pragma unroll
            for (int r = 0; r < 4; ++r)
                sh[(4 * q + r) * PITCH + nt * 16 + n] = C[nt][r];
        asm volatile("s_waitcnt lgkmcnt(0)" ::: "memory");

        // read back in A-layout (row = sentence n), fold emission, pack bf16
        {
            const float* p = sh + n * PITCH + q * 8;
            float4 lo = *(const float4*)p;
            float4 hi = *(const float4*)(p + 4);
            U8 f;
            f.u[0] = pk2(lo.x * lo16(e0a.x), lo.y * hi16(e0a.x));
            f.u[1] = pk2(lo.z * lo16(e0a.y), lo.w * hi16(e0a.y));
            f.u[2] = pk2(hi.x * lo16(e0a.z), hi.y * hi16(e0a.z));
            f.u[3] = pk2(hi.z * lo16(e0a.w), hi.w * hi16(e0a.w));
            Af0 = f.v;
        }
        {
            const float* p = sh + n * PITCH + 32 + q * 8;
            float4 lo = *(const float4*)p;
            float4 hi = *(const float4*)(p + 4);
            U8 f;
            f.u[0] = pk2(lo.x * lo16(e1a.x), lo.y * hi16(e1a.x));
            f.u[1] = pk2(lo.z * lo16(e1a.y), lo.w * hi16(e1a.y));
            f.u[2] = pk2(hi.x * lo16(e1a.z), hi.y * hi16(e1a.z));
            f.u[3] = pk2(hi.z * lo16(e1a.w), hi.w * hi16(e1a.w));
            Af1 = f.v;
        }
        e0a = e0b; e1a = e1b;
        e0b = e0c; e1b = e1c;
        e0c = e0d; e1c = e1d;
    }

    // logZ = log(sum_j alpha[j] * A[j][EOS]) - total scale
    f32x4 Cf = {0.f, 0.f, 0.f, 0.f};
    Cf = __builtin_amdgcn_mfma_f32_16x16x32_bf16(Af0, Bfin[0], Cf, 0, 0, 0);
    Cf = __builtin_amdgcn_mfma_f32_16x16x32_bf16(Af1, Bfin[1], Cf, 0, 0, 0);
    if (n == 0) {
#pragma unroll
        for (int r = 0; r < 4; ++r)
            out[b0 + 4 * q + r] = logf(Cf[r]) - LOG_TOTAL_SCALE;
    }
}

extern "C" void kernel_launch(void* const* d_in, const int* in_sizes, int n_in,
                              void* d_out, int out_size, void* d_ws, size_t ws_size,
                              hipStream_t stream) {
    const int*   words  = (const int*)d_in[0];     // [8192,126]
    const float* ThetaB = (const float*)d_in[1];   // [64,128]
    const float* WA     = (const float*)d_in[2];   // [64,64]
    const float* E      = (const float*)d_in[3];   // [50000,128]
    float* out = (float*)d_out;                    // [8192]

    char* ws = (char*)d_ws;
    unsigned short* btn_bf = (unsigned short*)(ws + BTN_OFF);
    float* A       = (float*)(ws + A_OFF);
    float* sumexp  = (float*)(ws + SUM_OFF);
    float* partial = (float*)(ws + PART_OFF);

    k_prepA<<<64, 64, 0, stream>>>(WA, A);
    k_emit<<<NBLK, 256, 0, stream>>>(ThetaB, E, btn_bf, partial);
    k_sum<<<KT, 256, 0, stream>>>(partial, sumexp);
    k_norm<<<(VV * KT / 8 + 255) / 256, 256, 0, stream>>>(btn_bf, sumexp);
    k_fwd<<<8192 / 16, 64, 0, stream>>>(words, btn_bf, A, out);
}